// Round 1
// baseline (269.715 us; speedup 1.0000x reference)
//
#include <hip/hip_runtime.h>

#define BATCH 4
#define SEQ   4096
#define CDIM  1024
#define DDIM  64

typedef _Float16 f16;
typedef _Float16 f16x8 __attribute__((ext_vector_type(8)));
typedef _Float16 f16x4 __attribute__((ext_vector_type(4)));
typedef float    f32x4 __attribute__((ext_vector_type(4)));

#define MFMA16(a, b, c) __builtin_amdgcn_mfma_f32_16x16x32_f16((a), (b), (c), 0, 0, 0)

// fold: scores = (q+bq)·k * 8 (the /scale bug) ; softmax via exp2 => fold 8*log2(e) into q
#define QSCALE 11.5415603f  // 8 * 1.44269504

// ---------------- W fp32 -> f16 prep ----------------
__global__ __launch_bounds__(256) void prep_w_kernel(const float* __restrict__ Wq,
                                                     const float* __restrict__ Wk,
                                                     const float* __restrict__ Wv,
                                                     f16* __restrict__ wf) {
  int i = blockIdx.x * 256 + threadIdx.x;   // grid covers 65536
  wf[i]          = (f16)Wq[i];
  wf[i + 65536]  = (f16)Wk[i];
  wf[i + 131072] = (f16)Wv[i];
}

// ---------------- fused QKV projection ----------------
// 1 wave/block, 32 rows/wave. q scaled+f16, k f16 [B,T,64]; v f16 transposed [B,64,T].
__global__ __launch_bounds__(64) void proj_kernel(const float* __restrict__ x,
                                                  const f16* __restrict__ wf,
                                                  const float* __restrict__ bq,
                                                  const float* __restrict__ bk,
                                                  const float* __restrict__ bv,
                                                  f16* __restrict__ qs,
                                                  f16* __restrict__ ks,
                                                  f16* __restrict__ vT) {
  const int lane = threadIdx.x;
  const int n = lane & 15, quad = lane >> 4;
  const int rowbase = blockIdx.x * 32;

  f32x4 acc[3][2][4];
#pragma unroll
  for (int m_ = 0; m_ < 3; ++m_)
#pragma unroll
    for (int rt = 0; rt < 2; ++rt)
#pragma unroll
      for (int t_ = 0; t_ < 4; ++t_) acc[m_][rt][t_] = (f32x4){0.f, 0.f, 0.f, 0.f};

  const float* xa0 = x + (size_t)(rowbase + n) * CDIM + quad * 8;
  const float* xa1 = xa0 + 16 * CDIM;

  for (int kc = 0; kc < CDIM; kc += 32) {
    f32x4 u0 = *(const f32x4*)(xa0 + kc);
    f32x4 u1 = *(const f32x4*)(xa0 + kc + 4);
    f32x4 w0 = *(const f32x4*)(xa1 + kc);
    f32x4 w1 = *(const f32x4*)(xa1 + kc + 4);
    f16x8 a0, a1;
#pragma unroll
    for (int j = 0; j < 4; ++j) {
      a0[j] = (f16)u0[j]; a0[4 + j] = (f16)u1[j];
      a1[j] = (f16)w0[j]; a1[4 + j] = (f16)w1[j];
    }
#pragma unroll
    for (int mat = 0; mat < 3; ++mat)
#pragma unroll
      for (int tile = 0; tile < 4; ++tile) {
        f16x8 bf = *(const f16x8*)(wf + (size_t)(mat * 64 + tile * 16 + n) * CDIM + kc + quad * 8);
        acc[mat][0][tile] = MFMA16(a0, bf, acc[mat][0][tile]);
        acc[mat][1][tile] = MFMA16(a1, bf, acc[mat][1][tile]);
      }
  }

  const float* bias_p[3] = {bq, bk, bv};
#pragma unroll
  for (int mat = 0; mat < 3; ++mat)
#pragma unroll
    for (int tile = 0; tile < 4; ++tile) {
      const int d = tile * 16 + n;
      const float bias = bias_p[mat][d];
#pragma unroll
      for (int rt = 0; rt < 2; ++rt) {
        const int row0 = rowbase + rt * 16 + quad * 4;   // C-layout: row=quad*4+r, col=n
        f32x4 a = acc[mat][rt][tile];
        if (mat == 0) {
#pragma unroll
          for (int r = 0; r < 4; ++r)
            qs[(size_t)(row0 + r) * DDIM + d] = (f16)((a[r] + bias) * QSCALE);
        } else if (mat == 1) {
#pragma unroll
          for (int r = 0; r < 4; ++r)
            ks[(size_t)(row0 + r) * DDIM + d] = (f16)(a[r] + bias);
        } else {
          const int bb = row0 >> 12;          // row0/4096
          const int t  = row0 & (SEQ - 1);
          f16x4 pk;
#pragma unroll
          for (int r = 0; r < 4; ++r) pk[r] = (f16)(a[r] + bias);
          *(f16x4*)(vT + (size_t)(bb * 64 + d) * SEQ + t) = pk;   // 8B store, t%4==0
        }
      }
    }
}

// ---------------- flash attention ----------------
// 4 waves/block, each wave: 16 q-rows, online softmax over 4096 keys in 32-key chunks.
__global__ __launch_bounds__(256) void attn_kernel(const f16* __restrict__ qs,
                                                   const f16* __restrict__ ks,
                                                   const f16* __restrict__ vT,
                                                   float* __restrict__ out) {
  __shared__ __attribute__((aligned(16))) f16 pb[4][16][40];  // per-wave P scratch, padded stride
  const int lane = threadIdx.x & 63;
  const int w = threadIdx.x >> 6;
  const int n = lane & 15, quad = lane >> 4;
  const int gw = blockIdx.x * 4 + w;     // 0..1023
  const int row0 = gw * 16;              // global q-row base (never crosses batch)
  const int bb = row0 >> 12;

  // persistent q A-fragments: A[m=lane&15][k=quad*8+j]
  const f16* qrow = qs + (size_t)(row0 + n) * DDIM + quad * 8;
  const f16x8 qlo = *(const f16x8*)qrow;
  const f16x8 qhi = *(const f16x8*)(qrow + 32);

  const f16* kb = ks + (size_t)bb * SEQ * DDIM;
  const f16* vb = vT + (size_t)bb * DDIM * SEQ;

  f32x4 acc[4];
  float mrow[4], lrow[4];
#pragma unroll
  for (int r = 0; r < 4; ++r) { mrow[r] = -1e30f; lrow[r] = 0.f; }
#pragma unroll
  for (int t_ = 0; t_ < 4; ++t_) acc[t_] = (f32x4){0.f, 0.f, 0.f, 0.f};

  for (int t0 = 0; t0 < SEQ; t0 += 32) {
    // k B-frags: B[k=d][nk] = k[t0+nk][d]  (rows of ks, 16B contiguous per lane)
    const f16* krow = kb + (size_t)(t0 + n) * DDIM + quad * 8;
    const f16x8 k0lo = *(const f16x8*)(krow);
    const f16x8 k0hi = *(const f16x8*)(krow + 32);
    const f16x8 k1lo = *(const f16x8*)(krow + 16 * DDIM);
    const f16x8 k1hi = *(const f16x8*)(krow + 16 * DDIM + 32);
    // v B-frags: B[k=s][nd] = v[t0+s][d] from vT rows, 16B contiguous per lane
    f16x8 vf[4];
#pragma unroll
    for (int tile = 0; tile < 4; ++tile)
      vf[tile] = *(const f16x8*)(vb + (size_t)(tile * 16 + n) * SEQ + t0 + quad * 8);

    // S tiles (log2-domain logits, scale folded into q)
    f32x4 s0 = (f32x4){0.f, 0.f, 0.f, 0.f}, s1 = (f32x4){0.f, 0.f, 0.f, 0.f};
    s0 = MFMA16(qlo, k0lo, s0);
    s0 = MFMA16(qhi, k0hi, s0);
    s1 = MFMA16(qlo, k1lo, s1);
    s1 = MFMA16(qhi, k1hi, s1);

    // online softmax per row r (row = quad*4+r), reduce across the 16 lanes of the quad
    float alpha[4];
#pragma unroll
    for (int r = 0; r < 4; ++r) {
      float mx = fmaxf(s0[r], s1[r]);
      mx = fmaxf(mx, __shfl_xor(mx, 1));
      mx = fmaxf(mx, __shfl_xor(mx, 2));
      mx = fmaxf(mx, __shfl_xor(mx, 4));
      mx = fmaxf(mx, __shfl_xor(mx, 8));
      const float mnew = fmaxf(mrow[r], mx);
      alpha[r] = __builtin_amdgcn_exp2f(mrow[r] - mnew);
      mrow[r] = mnew;
      const float p0 = __builtin_amdgcn_exp2f(s0[r] - mnew);
      const float p1 = __builtin_amdgcn_exp2f(s1[r] - mnew);
      float rs = p0 + p1;
      rs += __shfl_xor(rs, 1);
      rs += __shfl_xor(rs, 2);
      rs += __shfl_xor(rs, 4);
      rs += __shfl_xor(rs, 8);
      lrow[r] = lrow[r] * alpha[r] + rs;
      // stash P in C-layout -> LDS [row][col] (padded stride 40 halves)
      pb[w][quad * 4 + r][n]      = (f16)p0;
      pb[w][quad * 4 + r][16 + n] = (f16)p1;
    }
    // rescale O accumulator
#pragma unroll
    for (int tile = 0; tile < 4; ++tile) {
      acc[tile][0] *= alpha[0];
      acc[tile][1] *= alpha[1];
      acc[tile][2] *= alpha[2];
      acc[tile][3] *= alpha[3];
    }
    // P C-layout -> A-layout via LDS (same-wave DS ops are in-order; stop compiler motion)
    __builtin_amdgcn_wave_barrier();
    const f16x8 pa = *(const f16x8*)&pb[w][n][quad * 8];
#pragma unroll
    for (int tile = 0; tile < 4; ++tile)
      acc[tile] = MFMA16(pa, vf[tile], acc[tile]);
  }

#pragma unroll
  for (int r = 0; r < 4; ++r) {
    const float inv = 1.0f / lrow[r];
#pragma unroll
    for (int tile = 0; tile < 4; ++tile)
      out[(size_t)(row0 + quad * 4 + r) * DDIM + tile * 16 + n] = acc[tile][r] * inv;
  }
}

extern "C" void kernel_launch(void* const* d_in, const int* in_sizes, int n_in,
                              void* d_out, int out_size, void* d_ws, size_t ws_size,
                              hipStream_t stream) {
  const float* x  = (const float*)d_in[0];
  const float* Wq = (const float*)d_in[1];
  const float* bq = (const float*)d_in[2];
  const float* Wk = (const float*)d_in[3];
  const float* bk = (const float*)d_in[4];
  const float* Wv = (const float*)d_in[5];
  const float* bv = (const float*)d_in[6];
  float* out = (float*)d_out;

  f16* wf = (f16*)d_ws;                    // 3*64*1024 f16
  f16* qs = wf + 3 * 65536;                // [B,T,64] f16 (scaled)
  f16* ks = qs + (size_t)BATCH * SEQ * DDIM;
  f16* vT = ks + (size_t)BATCH * SEQ * DDIM;  // [B,64,T] f16

  prep_w_kernel<<<dim3(65536 / 256), dim3(256), 0, stream>>>(Wq, Wk, Wv, wf);
  proj_kernel<<<dim3(BATCH * SEQ / 32), dim3(64), 0, stream>>>(x, wf, bq, bk, bv, qs, ks, vT);
  attn_kernel<<<dim3(BATCH * SEQ / 16 / 4), dim3(256), 0, stream>>>(qs, ks, vT, out);
}

// Round 2
// 186.579 us; speedup vs baseline: 1.4456x; 1.4456x over previous
//
#include <hip/hip_runtime.h>

#define BATCH 4
#define SEQ   4096
#define CDIM  1024
#define DDIM  64
#define SP    72      // padded LDS row stride (f16) for 64-col tiles

typedef _Float16 f16;
typedef _Float16 f16x8 __attribute__((ext_vector_type(8)));
typedef _Float16 f16x4 __attribute__((ext_vector_type(4)));
typedef float    f32x4 __attribute__((ext_vector_type(4)));

#define MFMA16(a, b, c) __builtin_amdgcn_mfma_f32_16x16x32_f16((a), (b), (c), 0, 0, 0)

// scores = (q·k)*8 (the /scale bug); softmax in exp2 domain => fold 8*log2(e) into q
#define QSCALE 11.5415603f

// ---------------- W fp32 -> f16 prep ----------------
__global__ __launch_bounds__(256) void prep_w_kernel(const float* __restrict__ Wq,
                                                     const float* __restrict__ Wk,
                                                     const float* __restrict__ Wv,
                                                     f16* __restrict__ wf) {
  int i = blockIdx.x * 256 + threadIdx.x;
  wf[i]          = (f16)Wq[i];
  wf[i + 65536]  = (f16)Wk[i];
  wf[i + 131072] = (f16)Wv[i];
}

// ---------------- fused QKV projection ----------------
// 256 blocks x 256 thr; 4 waves x 16 rows = 64 rows/block. W chunk staged in LDS.
__global__ __launch_bounds__(256) void proj_kernel(const float* __restrict__ x,
                                                   const f16* __restrict__ wf,
                                                   const float* __restrict__ bq,
                                                   const float* __restrict__ bk,
                                                   const float* __restrict__ bv,
                                                   f16* __restrict__ qs,
                                                   f16* __restrict__ ks,
                                                   f16* __restrict__ vT) {
  __shared__ __attribute__((aligned(16))) f16 lw[192][SP];
  const int tid = threadIdx.x;
  const int lane = tid & 63, w = tid >> 6;
  const int n = lane & 15, quad = lane >> 4;
  const int rowbase = blockIdx.x * 64 + w * 16;

  // staging indices: 3 insts x 256 thr x 8 f16 = 6144 f16 = 192 rows x 32 cols
  const int srow = tid >> 2;        // 0..63 (+64*i)
  const int scol = (tid & 3) * 8;   // 0,8,16,24

  f32x4 acc[3][4];
#pragma unroll
  for (int m_ = 0; m_ < 3; ++m_)
#pragma unroll
    for (int t_ = 0; t_ < 4; ++t_) acc[m_][t_] = (f32x4){0.f, 0.f, 0.f, 0.f};

  const float* xrow = x + (size_t)(rowbase + n) * CDIM + quad * 8;

  f16x8 wreg[3];
  f32x4 xr0, xr1;
#define WLOAD(KC)                                                                    \
  {                                                                                  \
    _Pragma("unroll") for (int i = 0; i < 3; ++i)                                    \
        wreg[i] = *(const f16x8*)(wf + (size_t)(i * 64 + srow) * CDIM + (KC) + scol); \
  }
#define XLOAD(KC)                        \
  {                                      \
    xr0 = *(const f32x4*)(xrow + (KC));  \
    xr1 = *(const f32x4*)(xrow + (KC) + 4); \
  }

  WLOAD(0);
  XLOAD(0);
  for (int kc = 0; kc < CDIM; kc += 32) {
#pragma unroll
    for (int i = 0; i < 3; ++i) *(f16x8*)&lw[i * 64 + srow][scol] = wreg[i];
    __syncthreads();
    if (kc + 32 < CDIM) WLOAD(kc + 32);
    f16x8 a;
#pragma unroll
    for (int j = 0; j < 4; ++j) { a[j] = (f16)xr0[j]; a[4 + j] = (f16)xr1[j]; }
    if (kc + 32 < CDIM) XLOAD(kc + 32);
#pragma unroll
    for (int mat = 0; mat < 3; ++mat)
#pragma unroll
      for (int tile = 0; tile < 4; ++tile) {
        const f16x8 bf = *(const f16x8*)&lw[mat * 64 + tile * 16 + n][quad * 8];
        acc[mat][tile] = MFMA16(a, bf, acc[mat][tile]);
      }
    __syncthreads();
  }

  const float* bias_p[3] = {bq, bk, bv};
#pragma unroll
  for (int mat = 0; mat < 3; ++mat)
#pragma unroll
    for (int tile = 0; tile < 4; ++tile) {
      const int d = tile * 16 + n;
      const float bias = bias_p[mat][d];
      const int row0 = rowbase + quad * 4;   // C-layout: row=quad*4+r, col=n
      f32x4 a = acc[mat][tile];
      if (mat == 0) {
#pragma unroll
        for (int r = 0; r < 4; ++r)
          qs[(size_t)(row0 + r) * DDIM + d] = (f16)((a[r] + bias) * QSCALE);
      } else if (mat == 1) {
#pragma unroll
        for (int r = 0; r < 4; ++r)
          ks[(size_t)(row0 + r) * DDIM + d] = (f16)(a[r] + bias);
      } else {
        const int bb = row0 >> 12;
        const int t = row0 & (SEQ - 1);
        f16x4 pk;
#pragma unroll
        for (int r = 0; r < 4; ++r) pk[r] = (f16)(a[r] + bias);
        *(f16x4*)(vT + (size_t)(bb * 64 + d) * SEQ + t) = pk;
      }
    }
}

// ---------------- flash attention, LDS-staged K/V ----------------
// Block: 4 waves x 16 q-rows = 64 rows. Key chunks of 64 staged in LDS (shared).
// SPLIT2: 512 blocks, each covers half the keys; partials merged by combine_kernel.
template <bool SPLIT2>
__global__ __launch_bounds__(256) void attn_kernel(const f16* __restrict__ qs,
                                                   const f16* __restrict__ ks,
                                                   const f16* __restrict__ vT,
                                                   float* __restrict__ outp,
                                                   float* __restrict__ pm,
                                                   float* __restrict__ pl) {
  __shared__ __attribute__((aligned(16))) f16 lk[64][SP];   // [key][d]
  __shared__ __attribute__((aligned(16))) f16 lv[64][SP];   // [d][key]
  __shared__ __attribute__((aligned(16))) f16 pb[4][16][SP];

  const int tid = threadIdx.x;
  const int lane = tid & 63, w = tid >> 6;
  const int n = lane & 15, quad = lane >> 4;

  const int rowblk = SPLIT2 ? (blockIdx.x >> 1) : blockIdx.x;
  const int split  = SPLIT2 ? (blockIdx.x & 1) : 0;
  const int kbase  = split * (SEQ / 2);
  const int NC     = SPLIT2 ? (SEQ / 2 / 64) : (SEQ / 64);

  const int row0 = rowblk * 64 + w * 16;
  const int bb = row0 >> 12;

  const f16* qrow = qs + (size_t)(row0 + n) * DDIM + quad * 8;
  const f16x8 qlo = *(const f16x8*)qrow;
  const f16x8 qhi = *(const f16x8*)(qrow + 32);

  const f16* kb = ks + (size_t)bb * SEQ * DDIM;
  const f16* vb = vT + (size_t)bb * DDIM * SEQ;

  // staging: 256 thr x 16B x 4 insts = 16 KB (k 8KB + v 8KB)
  const int srow = tid >> 3;        // 0..31 (+32)
  const int scol = (tid & 7) * 8;   // 0..56

  f16x8 kr0, kr1, vr0, vr1;
#define LOADC(T0)                                                        \
  {                                                                      \
    kr0 = *(const f16x8*)(kb + (size_t)((T0) + srow) * DDIM + scol);     \
    kr1 = *(const f16x8*)(kb + (size_t)((T0) + srow + 32) * DDIM + scol);\
    vr0 = *(const f16x8*)(vb + (size_t)srow * SEQ + (T0) + scol);        \
    vr1 = *(const f16x8*)(vb + (size_t)(srow + 32) * SEQ + (T0) + scol); \
  }

  f32x4 acc[4];
  float mrow[4], llane[4];
#pragma unroll
  for (int r = 0; r < 4; ++r) { mrow[r] = -1e30f; llane[r] = 0.f; }
#pragma unroll
  for (int t_ = 0; t_ < 4; ++t_) acc[t_] = (f32x4){0.f, 0.f, 0.f, 0.f};

  LOADC(kbase);
  for (int c = 0; c < NC; ++c) {
    *(f16x8*)&lk[srow][scol] = kr0;
    *(f16x8*)&lk[srow + 32][scol] = kr1;
    *(f16x8*)&lv[srow][scol] = vr0;
    *(f16x8*)&lv[srow + 32][scol] = vr1;
    __syncthreads();
    if (c + 1 < NC) LOADC(kbase + (c + 1) * 64);

    // QK^T: 4 S-tiles of 16 keys
    f32x4 s[4];
#pragma unroll
    for (int st = 0; st < 4; ++st) {
      const f16x8 klo = *(const f16x8*)&lk[st * 16 + n][quad * 8];
      const f16x8 khi = *(const f16x8*)&lk[st * 16 + n][32 + quad * 8];
      f32x4 z = (f32x4){0.f, 0.f, 0.f, 0.f};
      z = MFMA16(qlo, klo, z);
      s[st] = MFMA16(qhi, khi, z);
    }

    // online softmax (exp2 domain); l kept per-lane (deferred reduction)
    float alpha[4];
#pragma unroll
    for (int r = 0; r < 4; ++r) {
      float mloc = fmaxf(fmaxf(s[0][r], s[1][r]), fmaxf(s[2][r], s[3][r]));
      mloc = fmaxf(mloc, __shfl_xor(mloc, 1));
      mloc = fmaxf(mloc, __shfl_xor(mloc, 2));
      mloc = fmaxf(mloc, __shfl_xor(mloc, 4));
      mloc = fmaxf(mloc, __shfl_xor(mloc, 8));
      const float mnew = fmaxf(mrow[r], mloc);
      alpha[r] = __builtin_amdgcn_exp2f(mrow[r] - mnew);
      mrow[r] = mnew;
      const float p0 = __builtin_amdgcn_exp2f(s[0][r] - mnew);
      const float p1 = __builtin_amdgcn_exp2f(s[1][r] - mnew);
      const float p2 = __builtin_amdgcn_exp2f(s[2][r] - mnew);
      const float p3 = __builtin_amdgcn_exp2f(s[3][r] - mnew);
      llane[r] = llane[r] * alpha[r] + ((p0 + p1) + (p2 + p3));
      const int prow = quad * 4 + r;
      pb[w][prow][n] = (f16)p0;
      pb[w][prow][16 + n] = (f16)p1;
      pb[w][prow][32 + n] = (f16)p2;
      pb[w][prow][48 + n] = (f16)p3;
    }
#pragma unroll
    for (int tile = 0; tile < 4; ++tile) {
      acc[tile][0] *= alpha[0];
      acc[tile][1] *= alpha[1];
      acc[tile][2] *= alpha[2];
      acc[tile][3] *= alpha[3];
    }
    __builtin_amdgcn_wave_barrier();
    const f16x8 pa0 = *(const f16x8*)&pb[w][n][quad * 8];
    const f16x8 pa1 = *(const f16x8*)&pb[w][n][32 + quad * 8];
#pragma unroll
    for (int tile = 0; tile < 4; ++tile) {
      const f16x8 vlo = *(const f16x8*)&lv[tile * 16 + n][quad * 8];
      const f16x8 vhi = *(const f16x8*)&lv[tile * 16 + n][32 + quad * 8];
      acc[tile] = MFMA16(pa0, vlo, acc[tile]);
      acc[tile] = MFMA16(pa1, vhi, acc[tile]);
    }
    __syncthreads();
  }

  // reduce per-lane l across the 16 lanes of the quad-row group
  float lred[4];
#pragma unroll
  for (int r = 0; r < 4; ++r) {
    float l = llane[r];
    l += __shfl_xor(l, 1);
    l += __shfl_xor(l, 2);
    l += __shfl_xor(l, 4);
    l += __shfl_xor(l, 8);
    lred[r] = l;
  }

  if (SPLIT2) {
    float* pacc = outp;  // partial acc buffer [2][16384][64]
#pragma unroll
    for (int r = 0; r < 4; ++r) {
      const int grow = row0 + quad * 4 + r;
#pragma unroll
      for (int tile = 0; tile < 4; ++tile)
        pacc[((size_t)split * BATCH * SEQ + grow) * DDIM + tile * 16 + n] = acc[tile][r];
      if (n == 0) {
        pm[split * BATCH * SEQ + grow] = mrow[r];
        pl[split * BATCH * SEQ + grow] = lred[r];
      }
    }
  } else {
#pragma unroll
    for (int r = 0; r < 4; ++r) {
      const float inv = 1.0f / lred[r];
      const int grow = row0 + quad * 4 + r;
#pragma unroll
      for (int tile = 0; tile < 4; ++tile)
        outp[(size_t)grow * DDIM + tile * 16 + n] = acc[tile][r] * inv;
    }
  }
}

// ---------------- split-K combine ----------------
__global__ __launch_bounds__(256) void combine_kernel(const float* __restrict__ pacc,
                                                      const float* __restrict__ pm,
                                                      const float* __restrict__ pl,
                                                      float* __restrict__ out) {
  const int idx = blockIdx.x * 256 + threadIdx.x;  // 16384*16 f32x4 units
  const int row = idx >> 4;
  const int c = (idx & 15) * 4;
  const float m0 = pm[row], m1 = pm[BATCH * SEQ + row];
  const float l0 = pl[row], l1 = pl[BATCH * SEQ + row];
  const float mm = fmaxf(m0, m1);
  const float e0 = __builtin_amdgcn_exp2f(m0 - mm);
  const float e1 = __builtin_amdgcn_exp2f(m1 - mm);
  const float inv = 1.0f / (l0 * e0 + l1 * e1);
  const f32x4 a0 = *(const f32x4*)(pacc + (size_t)row * DDIM + c);
  const f32x4 a1 = *(const f32x4*)(pacc + (size_t)(BATCH * SEQ + row) * DDIM + c);
  f32x4 o;
#pragma unroll
  for (int j = 0; j < 4; ++j) o[j] = (a0[j] * e0 + a1[j] * e1) * inv;
  *(f32x4*)(out + (size_t)row * DDIM + c) = o;
}

extern "C" void kernel_launch(void* const* d_in, const int* in_sizes, int n_in,
                              void* d_out, int out_size, void* d_ws, size_t ws_size,
                              hipStream_t stream) {
  const float* x  = (const float*)d_in[0];
  const float* Wq = (const float*)d_in[1];
  const float* bq = (const float*)d_in[2];
  const float* Wk = (const float*)d_in[3];
  const float* bk = (const float*)d_in[4];
  const float* Wv = (const float*)d_in[5];
  const float* bv = (const float*)d_in[6];
  float* out = (float*)d_out;

  f16* wf = (f16*)d_ws;
  f16* qs = wf + 3 * 65536;
  f16* ks = qs + (size_t)BATCH * SEQ * DDIM;
  f16* vT = ks + (size_t)BATCH * SEQ * DDIM;
  char* endf16 = (char*)(vT + (size_t)BATCH * SEQ * DDIM);

  float* pacc = (float*)endf16;                               // [2][B*T][64] f32
  float* pm   = pacc + (size_t)2 * BATCH * SEQ * DDIM;        // [2][B*T]
  float* pl   = pm + (size_t)2 * BATCH * SEQ;                 // [2][B*T]
  const size_t need = (size_t)((char*)(pl + (size_t)2 * BATCH * SEQ) - (char*)d_ws);
  const bool split2 = ws_size >= need;

  prep_w_kernel<<<dim3(256), dim3(256), 0, stream>>>(Wq, Wk, Wv, wf);
  proj_kernel<<<dim3(256), dim3(256), 0, stream>>>(x, wf, bq, bk, bv, qs, ks, vT);
  if (split2) {
    attn_kernel<true><<<dim3(512), dim3(256), 0, stream>>>(qs, ks, vT, pacc, pm, pl);
    combine_kernel<<<dim3(BATCH * SEQ * 16 / 256), dim3(256), 0, stream>>>(pacc, pm, pl, out);
  } else {
    attn_kernel<false><<<dim3(256), dim3(256), 0, stream>>>(qs, ks, vT, out, nullptr, nullptr);
  }
}